// Round 8
// baseline (4820.612 us; speedup 1.0000x reference)
//
#include <hip/hip_runtime.h>
#include <math.h>

// B=8, H=W=224, C=96, NH=3, HD=32, WS=7, SHIFT=3, N=49
// windows: 8192; tokens: 401408.  ZERO d_ws usage.
// Split-bf16 everywhere; ALL MFMA operands come from 16B memory loads
// (weight fragments via per-lane LDS bounce slots, volatile uint stores).

typedef short s8v __attribute__((ext_vector_type(8)));
typedef float f4v __attribute__((ext_vector_type(4)));

__device__ __forceinline__ ushort f2bf(float f) {
  union { float f; unsigned u; } v; v.f = f;
  unsigned r = v.u + 0x7fffu + ((v.u >> 16) & 1u);
  return (ushort)(r >> 16);
}
__device__ __forceinline__ float bf2f(ushort u) {
  union { unsigned u; float f; } v; v.u = ((unsigned)u) << 16;
  return v.f;
}
__device__ __forceinline__ f4v mfma16(s8v a, s8v b, f4v c) {
  return __builtin_amdgcn_mfma_f32_16x16x32_bf16(a, b, c, 0, 0, 0);
}

// Convert 8 strided fp32 -> split bf16 fragment pair, materialized through a
// per-lane LDS bounce slot (16B). No ext-vector element writes anywhere.
__device__ __forceinline__ void ldfragW(const float* __restrict__ p, int stride,
                                        uint* slotH, uint* slotL,
                                        s8v& h, s8v& l) {
  volatile uint* vh = slotH;
  volatile uint* vl = slotL;
  #pragma unroll
  for (int jj = 0; jj < 4; ++jj) {
    float a = p[(2 * jj) * stride];
    float b = p[(2 * jj + 1) * stride];
    ushort ha = f2bf(a), hb = f2bf(b);
    float ra = a - bf2f(ha), rb = b - bf2f(hb);
    vh[jj] = (uint)ha | ((uint)hb << 16);
    vl[jj] = (uint)f2bf(ra) | ((uint)f2bf(rb) << 16);
  }
  h = *(const s8v*)slotH;
  l = *(const s8v*)slotL;
}

// ---------------- window attention (round-2 structure, split-bf16) ----------------
// 1 window/block, 4 waves; wave w owns token-rows m = [16w, 16w+16).
__global__ __launch_bounds__(256) void win_attn_mfma(
    const float* __restrict__ x,
    const float* __restrict__ qkv_w, const float* __restrict__ qkv_b,
    const float* __restrict__ proj_w, const float* __restrict__ proj_b,
    const float* __restrict__ rpb,
    float* __restrict__ xr)
{
  __shared__ ushort XWH[64 * 104];  // X hi; aliased as P hi after phase 1
  __shared__ ushort XWL[64 * 104];  // X lo; aliased as P lo
  __shared__ ushort QH[64 * 104];   // Q hi (scaled); O hi overwrites per-head
  __shared__ ushort QL[64 * 104];   // Q lo
  __shared__ ushort KH[64 * 104];   // K hi
  __shared__ ushort KL2[64 * 104];  // K lo
  __shared__ ushort VTH[96 * 72];   // V^T hi: [d][t]
  __shared__ ushort VTL[96 * 72];   // V^T lo
  __shared__ uint   FragH[1024];    // per-thread 16B bounce slots
  __shared__ uint   FragL[1024];

  ushort* PH = XWH;  // [64][72] P hi (X dead after phase-1 barrier... see note)
  ushort* PL = XWL;

  const int tid = threadIdx.x;
  const int wave = tid >> 6, lane = tid & 63, g = lane >> 4, ln = lane & 15;
  const int m0 = 16 * wave;
  const int win = blockIdx.x;
  const int b = win >> 10, rem = win & 1023, wh = rem >> 5, ww = rem & 31;
  const float SCALE = 0.17677669529663687f;
  uint* slotH = &FragH[tid * 4];
  uint* slotL = &FragL[tid * 4];

  // ---- phase 0: load window (shift -3), rows >=49 zero, exact hi/lo split ----
  for (int idx = tid; idx < 64 * 24; idx += 256) {
    int t = idx / 24, c4 = (idx % 24) * 4;
    float4 v = make_float4(0.f, 0.f, 0.f, 0.f);
    if (t < 49) {
      int i = t / 7, j = t % 7;
      int hh = wh * 7 + i + 3; if (hh >= 224) hh -= 224;
      int wc = ww * 7 + j + 3; if (wc >= 224) wc -= 224;
      v = *(const float4*)(x + ((size_t)(b * 224 + hh) * 224 + wc) * 96 + c4);
    }
    ushort4 uh, ul;
    uh.x = f2bf(v.x); ul.x = f2bf(v.x - bf2f(uh.x));
    uh.y = f2bf(v.y); ul.y = f2bf(v.y - bf2f(uh.y));
    uh.z = f2bf(v.z); ul.z = f2bf(v.z - bf2f(uh.z));
    uh.w = f2bf(v.w); ul.w = f2bf(v.w - bf2f(uh.w));
    *(ushort4*)&XWH[t * 104 + c4] = uh;
    *(ushort4*)&XWL[t * 104 + c4] = ul;
  }
  __syncthreads();

  // ---- phase 1: qkv GEMM (own m-tile rows, 18 col-tiles, K=96), 3-term split ----
  {
    s8v axh[3], axl[3];
    #pragma unroll
    for (int kt = 0; kt < 3; ++kt) {
      axh[kt] = *(const s8v*)&XWH[(m0 + ln) * 104 + kt * 32 + 8 * g];
      axl[kt] = *(const s8v*)&XWL[(m0 + ln) * 104 + kt * 32 + 8 * g];
    }
    for (int ct = 0; ct < 18; ++ct) {
      int c = ct * 16 + ln;
      f4v acc = {0.f, 0.f, 0.f, 0.f};
      #pragma unroll
      for (int kt = 0; kt < 3; ++kt) {
        s8v Bh, Bl;  // B[k][c] = qkv_w[k*288 + c], k = kt*32+8g+j
        ldfragW(qkv_w + (kt * 32 + 8 * g) * 288 + c, 288, slotH, slotL, Bh, Bl);
        acc = mfma16(axh[kt], Bh, acc);
        acc = mfma16(axl[kt], Bh, acc);
        acc = mfma16(axh[kt], Bl, acc);
      }
      float bias = qkv_b[c];
      int seg = (c >= 192) ? 2 : (c >= 96 ? 1 : 0);
      int cc = c - seg * 96;
      #pragma unroll
      for (int r = 0; r < 4; ++r) {
        int m = m0 + 4 * g + r;
        float val = acc[r] + bias;
        ushort hi, lo;
        if (seg == 0) {
          val *= SCALE;
          hi = f2bf(val); lo = f2bf(val - bf2f(hi));
          QH[m * 104 + cc] = hi; QL[m * 104 + cc] = lo;
        } else if (seg == 1) {
          hi = f2bf(val); lo = f2bf(val - bf2f(hi));
          KH[m * 104 + cc] = hi; KL2[m * 104 + cc] = lo;
        } else {
          hi = f2bf(val); lo = f2bf(val - bf2f(hi));
          VTH[cc * 72 + m] = hi; VTL[cc * 72 + m] = lo;
        }
      }
    }
  }
  __syncthreads();  // K, V^T shared across waves; X space becomes P space

  // ---- phase 2: per head: S = Q·K^T -> softmax -> O = P·V ----
  for (int h3 = 0; h3 < 3; ++h3) {
    const int hb = 32 * h3;
    s8v aqh = *(const s8v*)&QH[(m0 + ln) * 104 + hb + 8 * g];
    s8v aql = *(const s8v*)&QL[(m0 + ln) * 104 + hb + 8 * g];
    f4v sv[4];
    #pragma unroll
    for (int st = 0; st < 4; ++st) {
      s8v bkh = *(const s8v*)&KH[(st * 16 + ln) * 104 + hb + 8 * g];
      s8v bkl = *(const s8v*)&KL2[(st * 16 + ln) * 104 + hb + 8 * g];
      f4v z = {0.f, 0.f, 0.f, 0.f};
      z = mfma16(aqh, bkh, z);
      z = mfma16(aql, bkh, z);
      z = mfma16(aqh, bkl, z);
      sv[st] = z;  // S[m0+4g+r][st*16+ln]
    }
    #pragma unroll
    for (int r = 0; r < 4; ++r) {
      int m = m0 + 4 * g + r;
      bool mok = (m < 49);
      int mm = mok ? m : 0;
      int ti = mm / 7, tj = mm % 7;
      float mx = -1e30f;
      #pragma unroll
      for (int st = 0; st < 4; ++st) {
        int s = st * 16 + ln;
        float v = sv[st][r];
        if (s < 49 && mok) {
          int si = s / 7, sj = s % 7;
          v += rpb[((ti - si + 6) * 13 + (tj - sj + 6)) * 3 + h3];
        }
        if (s >= 49) v = -1e30f;
        sv[st][r] = v;
        mx = fmaxf(mx, v);
      }
      #pragma unroll
      for (int o = 1; o < 16; o <<= 1) mx = fmaxf(mx, __shfl_xor(mx, o));
      float sum = 0.f;
      #pragma unroll
      for (int st = 0; st < 4; ++st) {
        int s = st * 16 + ln;
        float e = (s < 49) ? __expf(sv[st][r] - mx) : 0.f;
        sv[st][r] = e; sum += e;
      }
      #pragma unroll
      for (int o = 1; o < 16; o <<= 1) sum += __shfl_xor(sum, o);
      float inv = 1.f / sum;
      #pragma unroll
      for (int st = 0; st < 4; ++st) {
        int s = st * 16 + ln;
        float pv = sv[st][r] * inv;
        ushort hi = f2bf(pv), lo = f2bf(pv - bf2f(hi));
        PH[m * 72 + s] = hi; PL[m * 72 + s] = lo;   // wave-private rows
      }
    }
    // PV: A = P rows (own), B = V^T fragment
    s8v aph[2], apl[2];
    #pragma unroll
    for (int ks = 0; ks < 2; ++ks) {
      aph[ks] = *(const s8v*)&PH[(m0 + ln) * 72 + ks * 32 + 8 * g];
      apl[ks] = *(const s8v*)&PL[(m0 + ln) * 72 + ks * 32 + 8 * g];
    }
    #pragma unroll
    for (int dt = 0; dt < 2; ++dt) {
      f4v oa = {0.f, 0.f, 0.f, 0.f};
      #pragma unroll
      for (int ks = 0; ks < 2; ++ks) {
        const int vrow = (hb + dt * 16 + ln) * 72 + ks * 32 + 8 * g;
        s8v bvh = *(const s8v*)&VTH[vrow];
        s8v bvl = *(const s8v*)&VTL[vrow];
        oa = mfma16(aph[ks], bvh, oa);
        oa = mfma16(apl[ks], bvh, oa);
        oa = mfma16(aph[ks], bvl, oa);
      }
      #pragma unroll
      for (int r = 0; r < 4; ++r) {
        int m = m0 + 4 * g + r;
        ushort hi = f2bf(oa[r]), lo = f2bf(oa[r] - bf2f(hi));
        QH[m * 104 + hb + dt * 16 + ln] = hi;  // O overwrites Q (own rows,
        QL[m * 104 + hb + dt * 16 + ln] = lo;  //  cols of this head, post-read)
      }
    }
  }

  // ---- phase 3: proj + scatter (reverse shift) ----
  {
    s8v aoh[3], aol[3];
    #pragma unroll
    for (int kb = 0; kb < 3; ++kb) {
      aoh[kb] = *(const s8v*)&QH[(m0 + ln) * 104 + kb * 32 + 8 * g];
      aol[kb] = *(const s8v*)&QL[(m0 + ln) * 104 + kb * 32 + 8 * g];
    }
    #pragma unroll
    for (int nt = 0; nt < 6; ++nt) {
      int c = nt * 16 + ln;
      f4v acc = {0.f, 0.f, 0.f, 0.f};
      #pragma unroll
      for (int kb = 0; kb < 3; ++kb) {
        s8v Bh, Bl;  // B[k][c] = proj_w[k*96 + c], k = kb*32+8g+j
        ldfragW(proj_w + (kb * 32 + 8 * g) * 96 + c, 96, slotH, slotL, Bh, Bl);
        acc = mfma16(aoh[kb], Bh, acc);
        acc = mfma16(aol[kb], Bh, acc);
        acc = mfma16(aoh[kb], Bl, acc);
      }
      float pb = proj_b[c];
      #pragma unroll
      for (int r = 0; r < 4; ++r) {
        int m = m0 + 4 * g + r;
        if (m < 49) {
          int i = m / 7, j = m % 7;
          int hh = wh * 7 + i + 3; if (hh >= 224) hh -= 224;
          int wv = ww * 7 + j + 3; if (wv >= 224) wv -= 224;
          xr[((size_t)(b * 224 + hh) * 224 + wv) * 96 + c] = acc[r] + pb;
        }
      }
    }
  }
}

// ---------------- LN + MLP (split-bf16 MFMA), in-place ----------------
// 64 tokens/block, 4 waves; wave w owns tokens [16w,16w+16).
__global__ __launch_bounds__(256) void mlp_mfma(
    float* __restrict__ io, const float* __restrict__ gg, const float* __restrict__ bb,
    const float* __restrict__ fc1_w, const float* __restrict__ fc1_b,
    const float* __restrict__ fc2_w, const float* __restrict__ fc2_b)
{
  __shared__ ushort XH[64 * 96], XL[64 * 96];          // normalized tokens hi/lo
  __shared__ ushort HH[4][16 * 200], HL[4][16 * 200];  // per-wave gelu(fc1) hi/lo
  __shared__ uint   FragH[1024], FragL[1024];

  const int tid = threadIdx.x;
  const int wave = tid >> 6, lane = tid & 63, gq = lane >> 4, ln = lane & 15;
  const int m0 = wave * 16;
  const size_t base = (size_t)blockIdx.x * 64 * 96;
  uint* slotH = &FragH[tid * 4];
  uint* slotL = &FragL[tid * 4];

  // LN: 4 threads/token (wave-private tokens)
  {
    const int tt = tid >> 2, q = tid & 3;
    const float* xp = io + base + (size_t)tt * 96 + q * 24;
    float4 v[6];
    #pragma unroll
    for (int i = 0; i < 6; ++i) v[i] = *(const float4*)(xp + i * 4);
    float s = 0.f, s2 = 0.f;
    #pragma unroll
    for (int i = 0; i < 6; ++i) {
      s  += v[i].x + v[i].y + v[i].z + v[i].w;
      s2 += v[i].x * v[i].x + v[i].y * v[i].y + v[i].z * v[i].z + v[i].w * v[i].w;
    }
    s  += __shfl_xor(s, 1);  s  += __shfl_xor(s, 2);
    s2 += __shfl_xor(s2, 1); s2 += __shfl_xor(s2, 2);
    float mu  = s * (1.f / 96.f);
    float inv = rsqrtf(s2 * (1.f / 96.f) - mu * mu + 1e-5f);
    #pragma unroll
    for (int i = 0; i < 6; ++i) {
      int c = q * 24 + i * 4;
      float n0 = (v[i].x - mu) * inv * gg[c + 0] + bb[c + 0];
      float n1 = (v[i].y - mu) * inv * gg[c + 1] + bb[c + 1];
      float n2 = (v[i].z - mu) * inv * gg[c + 2] + bb[c + 2];
      float n3 = (v[i].w - mu) * inv * gg[c + 3] + bb[c + 3];
      ushort4 uh, ul;
      uh.x = f2bf(n0); ul.x = f2bf(n0 - bf2f(uh.x));
      uh.y = f2bf(n1); ul.y = f2bf(n1 - bf2f(uh.y));
      uh.z = f2bf(n2); ul.z = f2bf(n2 - bf2f(uh.z));
      uh.w = f2bf(n3); ul.w = f2bf(n3 - bf2f(uh.w));
      *(ushort4*)&XH[tt * 96 + c] = uh;
      *(ushort4*)&XL[tt * 96 + c] = ul;
    }
  }

  f4v oacc[6];
  #pragma unroll
  for (int nt = 0; nt < 6; ++nt) oacc[nt] = (f4v){0.f, 0.f, 0.f, 0.f};

  ushort* Hh = HH[wave];
  ushort* Hl = HL[wave];
  s8v axh[3], axl[3];
  #pragma unroll
  for (int kt = 0; kt < 3; ++kt) {
    axh[kt] = *(const s8v*)&XH[(m0 + ln) * 96 + kt * 32 + 8 * gq];
    axl[kt] = *(const s8v*)&XL[(m0 + ln) * 96 + kt * 32 + 8 * gq];
  }

  #pragma unroll
  for (int ph = 0; ph < 2; ++ph) {
    // fc1 half (192 cols) + exact gelu, split stores
    #pragma unroll
    for (int nt = 0; nt < 12; ++nt) {
      int cg = ph * 192 + nt * 16 + ln;
      f4v acc = {0.f, 0.f, 0.f, 0.f};
      #pragma unroll
      for (int kt = 0; kt < 3; ++kt) {
        s8v Bh, Bl;  // B[k][cg] = fc1_w[k*384 + cg], k = kt*32+8gq+j
        ldfragW(fc1_w + (kt * 32 + 8 * gq) * 384 + cg, 384, slotH, slotL, Bh, Bl);
        acc = mfma16(axh[kt], Bh, acc);
        acc = mfma16(axl[kt], Bh, acc);
        acc = mfma16(axh[kt], Bl, acc);
      }
      float fb = fc1_b[cg];
      #pragma unroll
      for (int r = 0; r < 4; ++r) {
        float u = acc[r] + fb;
        float ge = 0.5f * u * (1.f + erff(u * 0.70710678118654752f));
        ushort hi = f2bf(ge), lo = f2bf(ge - bf2f(hi));
        Hh[(4 * gq + r) * 200 + nt * 16 + ln] = hi;
        Hl[(4 * gq + r) * 200 + nt * 16 + ln] = lo;
      }
    }
    // fc2 partial over this half's K range
    #pragma unroll
    for (int kk = 0; kk < 6; ++kk) {
      s8v Ahh = *(const s8v*)&Hh[ln * 200 + kk * 32 + 8 * gq];
      s8v Ahl = *(const s8v*)&Hl[ln * 200 + kk * 32 + 8 * gq];
      #pragma unroll
      for (int nt = 0; nt < 6; ++nt) {
        s8v Bh, Bl;  // B[k][c] = fc2_w[k*96 + c], k = ph*192+kk*32+8gq+j
        ldfragW(fc2_w + (ph * 192 + kk * 32 + 8 * gq) * 96 + nt * 16 + ln, 96,
                slotH, slotL, Bh, Bl);
        oacc[nt] = mfma16(Ahh, Bh, oacc[nt]);
        oacc[nt] = mfma16(Ahl, Bh, oacc[nt]);
        oacc[nt] = mfma16(Ahh, Bl, oacc[nt]);
      }
    }
  }

  // residual + write
  #pragma unroll
  for (int nt = 0; nt < 6; ++nt) {
    int c = nt * 16 + ln;
    float fb = fc2_b[c];
    #pragma unroll
    for (int r = 0; r < 4; ++r) {
      int m = m0 + 4 * gq + r;
      size_t a = base + (size_t)m * 96 + c;
      io[a] = io[a] + oacc[nt][r] + fb;
    }
  }
}

extern "C" void kernel_launch(void* const* d_in, const int* in_sizes, int n_in,
                              void* d_out, int out_size, void* d_ws, size_t ws_size,
                              hipStream_t stream) {
  const float* x      = (const float*)d_in[0];
  const float* qkv_w  = (const float*)d_in[1];
  const float* qkv_b  = (const float*)d_in[2];
  const float* proj_w = (const float*)d_in[3];
  const float* proj_b = (const float*)d_in[4];
  const float* rpb    = (const float*)d_in[5];
  const float* n2g    = (const float*)d_in[6];
  const float* n2b    = (const float*)d_in[7];
  const float* fc1_w  = (const float*)d_in[8];
  const float* fc1_b  = (const float*)d_in[9];
  const float* fc2_w  = (const float*)d_in[10];
  const float* fc2_b  = (const float*)d_in[11];
  float* out = (float*)d_out;

  // K1: window attention -> writes xr (pre-MLP) into d_out (full overwrite)
  win_attn_mfma<<<8192, 256, 0, stream>>>(x, qkv_w, qkv_b, proj_w, proj_b, rpb, out);
  // K2: LN + MLP + residual, in-place on d_out
  mlp_mfma<<<6272, 256, 0, stream>>>(out, n2g, n2b, fc1_w, fc1_b, fc2_w, fc2_b);
}

// Round 10
// 2946.610 us; speedup vs baseline: 1.6360x; 1.6360x over previous
//
#include <hip/hip_runtime.h>
#include <math.h>

// B=8, H=W=224, C=96, NH=3, HD=32, WS=7, SHIFT=3, N=49
// windows: 8192; tokens: 401408.  ZERO d_ws usage.
// Certified MFMA operand rule (r1/r2/r8 vs r5/r6/r7/r9 evidence): operands must
// be read as whole 16B vectors from LDS/global written via plain scalar stores.
// NEVER assemble ext-vector fragments element-wise in registers.

typedef short s8v __attribute__((ext_vector_type(8)));
typedef float f4v __attribute__((ext_vector_type(4)));

__device__ __forceinline__ ushort f2bf(float f) {
  union { float f; unsigned u; } v; v.f = f;
  unsigned r = v.u + 0x7fffu + ((v.u >> 16) & 1u);
  return (ushort)(r >> 16);
}
__device__ __forceinline__ float bf2f(ushort u) {
  union { unsigned u; float f; } v; v.u = ((unsigned)u) << 16;
  return v.f;
}
__device__ __forceinline__ f4v mfma16(s8v a, s8v b, f4v c) {
  return __builtin_amdgcn_mfma_f32_16x16x32_bf16(a, b, c, 0, 0, 0);
}

// ---- attn-only fallback: strided fp32 -> split fragment pair via LDS bounce ----
__device__ __forceinline__ void ldfragW(const float* __restrict__ p, int stride,
                                        uint* slotH, uint* slotL,
                                        s8v& h, s8v& l) {
  volatile uint* vh = slotH;
  volatile uint* vl = slotL;
  #pragma unroll
  for (int jj = 0; jj < 4; ++jj) {
    float a = p[(2 * jj) * stride];
    float b = p[(2 * jj + 1) * stride];
    ushort ha = f2bf(a), hb = f2bf(b);
    float ra = a - bf2f(ha), rb = b - bf2f(hb);
    vh[jj] = (uint)ha | ((uint)hb << 16);
    vl[jj] = (uint)f2bf(ra) | ((uint)f2bf(rb) << 16);
  }
  h = *(const s8v*)slotH;
  l = *(const s8v*)slotL;
}

// ---------------- window attention (round-8 GREEN kernel, verbatim) ----------------
__global__ __launch_bounds__(256) void win_attn_mfma(
    const float* __restrict__ x,
    const float* __restrict__ qkv_w, const float* __restrict__ qkv_b,
    const float* __restrict__ proj_w, const float* __restrict__ proj_b,
    const float* __restrict__ rpb,
    float* __restrict__ xr)
{
  __shared__ ushort XWH[64 * 104];
  __shared__ ushort XWL[64 * 104];
  __shared__ ushort QH[64 * 104];
  __shared__ ushort QL[64 * 104];
  __shared__ ushort KH[64 * 104];
  __shared__ ushort KL2[64 * 104];
  __shared__ ushort VTH[96 * 72];
  __shared__ ushort VTL[96 * 72];
  __shared__ uint   FragH[1024];
  __shared__ uint   FragL[1024];

  ushort* PH = XWH;
  ushort* PL = XWL;

  const int tid = threadIdx.x;
  const int wave = tid >> 6, lane = tid & 63, g = lane >> 4, ln = lane & 15;
  const int m0 = 16 * wave;
  const int win = blockIdx.x;
  const int b = win >> 10, rem = win & 1023, wh = rem >> 5, ww = rem & 31;
  const float SCALE = 0.17677669529663687f;
  uint* slotH = &FragH[tid * 4];
  uint* slotL = &FragL[tid * 4];

  for (int idx = tid; idx < 64 * 24; idx += 256) {
    int t = idx / 24, c4 = (idx % 24) * 4;
    float4 v = make_float4(0.f, 0.f, 0.f, 0.f);
    if (t < 49) {
      int i = t / 7, j = t % 7;
      int hh = wh * 7 + i + 3; if (hh >= 224) hh -= 224;
      int wc = ww * 7 + j + 3; if (wc >= 224) wc -= 224;
      v = *(const float4*)(x + ((size_t)(b * 224 + hh) * 224 + wc) * 96 + c4);
    }
    ushort4 uh, ul;
    uh.x = f2bf(v.x); ul.x = f2bf(v.x - bf2f(uh.x));
    uh.y = f2bf(v.y); ul.y = f2bf(v.y - bf2f(uh.y));
    uh.z = f2bf(v.z); ul.z = f2bf(v.z - bf2f(uh.z));
    uh.w = f2bf(v.w); ul.w = f2bf(v.w - bf2f(uh.w));
    *(ushort4*)&XWH[t * 104 + c4] = uh;
    *(ushort4*)&XWL[t * 104 + c4] = ul;
  }
  __syncthreads();

  {
    s8v axh[3], axl[3];
    #pragma unroll
    for (int kt = 0; kt < 3; ++kt) {
      axh[kt] = *(const s8v*)&XWH[(m0 + ln) * 104 + kt * 32 + 8 * g];
      axl[kt] = *(const s8v*)&XWL[(m0 + ln) * 104 + kt * 32 + 8 * g];
    }
    for (int ct = 0; ct < 18; ++ct) {
      int c = ct * 16 + ln;
      f4v acc = {0.f, 0.f, 0.f, 0.f};
      #pragma unroll
      for (int kt = 0; kt < 3; ++kt) {
        s8v Bh, Bl;
        ldfragW(qkv_w + (kt * 32 + 8 * g) * 288 + c, 288, slotH, slotL, Bh, Bl);
        acc = mfma16(axh[kt], Bh, acc);
        acc = mfma16(axl[kt], Bh, acc);
        acc = mfma16(axh[kt], Bl, acc);
      }
      float bias = qkv_b[c];
      int seg = (c >= 192) ? 2 : (c >= 96 ? 1 : 0);
      int cc = c - seg * 96;
      #pragma unroll
      for (int r = 0; r < 4; ++r) {
        int m = m0 + 4 * g + r;
        float val = acc[r] + bias;
        ushort hi, lo;
        if (seg == 0) {
          val *= SCALE;
          hi = f2bf(val); lo = f2bf(val - bf2f(hi));
          QH[m * 104 + cc] = hi; QL[m * 104 + cc] = lo;
        } else if (seg == 1) {
          hi = f2bf(val); lo = f2bf(val - bf2f(hi));
          KH[m * 104 + cc] = hi; KL2[m * 104 + cc] = lo;
        } else {
          hi = f2bf(val); lo = f2bf(val - bf2f(hi));
          VTH[cc * 72 + m] = hi; VTL[cc * 72 + m] = lo;
        }
      }
    }
  }
  __syncthreads();

  for (int h3 = 0; h3 < 3; ++h3) {
    const int hb = 32 * h3;
    s8v aqh = *(const s8v*)&QH[(m0 + ln) * 104 + hb + 8 * g];
    s8v aql = *(const s8v*)&QL[(m0 + ln) * 104 + hb + 8 * g];
    f4v sv[4];
    #pragma unroll
    for (int st = 0; st < 4; ++st) {
      s8v bkh = *(const s8v*)&KH[(st * 16 + ln) * 104 + hb + 8 * g];
      s8v bkl = *(const s8v*)&KL2[(st * 16 + ln) * 104 + hb + 8 * g];
      f4v z = {0.f, 0.f, 0.f, 0.f};
      z = mfma16(aqh, bkh, z);
      z = mfma16(aql, bkh, z);
      z = mfma16(aqh, bkl, z);
      sv[st] = z;
    }
    #pragma unroll
    for (int r = 0; r < 4; ++r) {
      int m = m0 + 4 * g + r;
      bool mok = (m < 49);
      int mm = mok ? m : 0;
      int ti = mm / 7, tj = mm % 7;
      float mx = -1e30f;
      #pragma unroll
      for (int st = 0; st < 4; ++st) {
        int s = st * 16 + ln;
        float v = sv[st][r];
        if (s < 49 && mok) {
          int si = s / 7, sj = s % 7;
          v += rpb[((ti - si + 6) * 13 + (tj - sj + 6)) * 3 + h3];
        }
        if (s >= 49) v = -1e30f;
        sv[st][r] = v;
        mx = fmaxf(mx, v);
      }
      #pragma unroll
      for (int o = 1; o < 16; o <<= 1) mx = fmaxf(mx, __shfl_xor(mx, o));
      float sum = 0.f;
      #pragma unroll
      for (int st = 0; st < 4; ++st) {
        int s = st * 16 + ln;
        float e = (s < 49) ? __expf(sv[st][r] - mx) : 0.f;
        sv[st][r] = e; sum += e;
      }
      #pragma unroll
      for (int o = 1; o < 16; o <<= 1) sum += __shfl_xor(sum, o);
      float inv = 1.f / sum;
      #pragma unroll
      for (int st = 0; st < 4; ++st) {
        int s = st * 16 + ln;
        float pv = sv[st][r] * inv;
        ushort hi = f2bf(pv), lo = f2bf(pv - bf2f(hi));
        PH[m * 72 + s] = hi; PL[m * 72 + s] = lo;
      }
    }
    s8v aph[2], apl[2];
    #pragma unroll
    for (int ks = 0; ks < 2; ++ks) {
      aph[ks] = *(const s8v*)&PH[(m0 + ln) * 72 + ks * 32 + 8 * g];
      apl[ks] = *(const s8v*)&PL[(m0 + ln) * 72 + ks * 32 + 8 * g];
    }
    #pragma unroll
    for (int dt = 0; dt < 2; ++dt) {
      f4v oa = {0.f, 0.f, 0.f, 0.f};
      #pragma unroll
      for (int ks = 0; ks < 2; ++ks) {
        const int vrow = (hb + dt * 16 + ln) * 72 + ks * 32 + 8 * g;
        s8v bvh = *(const s8v*)&VTH[vrow];
        s8v bvl = *(const s8v*)&VTL[vrow];
        oa = mfma16(aph[ks], bvh, oa);
        oa = mfma16(apl[ks], bvh, oa);
        oa = mfma16(aph[ks], bvl, oa);
      }
      #pragma unroll
      for (int r = 0; r < 4; ++r) {
        int m = m0 + 4 * g + r;
        ushort hi = f2bf(oa[r]), lo = f2bf(oa[r] - bf2f(hi));
        QH[m * 104 + hb + dt * 16 + ln] = hi;
        QL[m * 104 + hb + dt * 16 + ln] = lo;
      }
    }
  }

  {
    s8v aoh[3], aol[3];
    #pragma unroll
    for (int kb = 0; kb < 3; ++kb) {
      aoh[kb] = *(const s8v*)&QH[(m0 + ln) * 104 + kb * 32 + 8 * g];
      aol[kb] = *(const s8v*)&QL[(m0 + ln) * 104 + kb * 32 + 8 * g];
    }
    #pragma unroll
    for (int nt = 0; nt < 6; ++nt) {
      int c = nt * 16 + ln;
      f4v acc = {0.f, 0.f, 0.f, 0.f};
      #pragma unroll
      for (int kb = 0; kb < 3; ++kb) {
        s8v Bh, Bl;
        ldfragW(proj_w + (kb * 32 + 8 * g) * 96 + c, 96, slotH, slotL, Bh, Bl);
        acc = mfma16(aoh[kb], Bh, acc);
        acc = mfma16(aol[kb], Bh, acc);
        acc = mfma16(aoh[kb], Bl, acc);
      }
      float pb = proj_b[c];
      #pragma unroll
      for (int r = 0; r < 4; ++r) {
        int m = m0 + 4 * g + r;
        if (m < 49) {
          int i = m / 7, j = m % 7;
          int hh = wh * 7 + i + 3; if (hh >= 224) hh -= 224;
          int wv = ww * 7 + j + 3; if (wv >= 224) wv -= 224;
          xr[((size_t)(b * 224 + hh) * 224 + wv) * 96 + c] = acc[r] + pb;
        }
      }
    }
  }
}

// ---------------- LN + MLP: block-staged weight tiles in LDS ----------------
// 128 tokens/block, 8 waves (512 thr); wave w owns tokens [16w,16w+16).
// Weight tile [96 cols][k:32 pad 40] hi/lo staged cooperatively per (quarter,ktile);
// accumulation order identical to round 8 -> bitwise-identical output.
__global__ __launch_bounds__(512) void mlp_mfma(
    float* __restrict__ io, const float* __restrict__ gg, const float* __restrict__ bb,
    const float* __restrict__ fc1_w, const float* __restrict__ fc1_b,
    const float* __restrict__ fc2_w, const float* __restrict__ fc2_b)
{
  __shared__ ushort XH[128 * 104], XL[128 * 104];      // normalized tokens hi/lo
  __shared__ ushort HH[8][16 * 104], HL[8][16 * 104];  // per-wave quarter gelu(fc1)
  __shared__ ushort WH[96 * 40], WL[96 * 40];          // staged weight tile

  const int tid = threadIdx.x;
  const int wave = tid >> 6, lane = tid & 63, gq = lane >> 4, ln = lane & 15;
  const int m0 = wave * 16;
  const size_t base = (size_t)blockIdx.x * 128 * 96;

  // LN: 4 threads/token (wave-private tokens; in-wave LDS write->read only)
  {
    const int tt = tid >> 2, q = tid & 3;
    const float* xp = io + base + (size_t)tt * 96 + q * 24;
    float4 v[6];
    #pragma unroll
    for (int i = 0; i < 6; ++i) v[i] = *(const float4*)(xp + i * 4);
    float s = 0.f, s2 = 0.f;
    #pragma unroll
    for (int i = 0; i < 6; ++i) {
      s  += v[i].x + v[i].y + v[i].z + v[i].w;
      s2 += v[i].x * v[i].x + v[i].y * v[i].y + v[i].z * v[i].z + v[i].w * v[i].w;
    }
    s  += __shfl_xor(s, 1);  s  += __shfl_xor(s, 2);
    s2 += __shfl_xor(s2, 1); s2 += __shfl_xor(s2, 2);
    float mu  = s * (1.f / 96.f);
    float inv = rsqrtf(s2 * (1.f / 96.f) - mu * mu + 1e-5f);
    #pragma unroll
    for (int i = 0; i < 6; ++i) {
      int c = q * 24 + i * 4;
      float n0 = (v[i].x - mu) * inv * gg[c + 0] + bb[c + 0];
      float n1 = (v[i].y - mu) * inv * gg[c + 1] + bb[c + 1];
      float n2 = (v[i].z - mu) * inv * gg[c + 2] + bb[c + 2];
      float n3 = (v[i].w - mu) * inv * gg[c + 3] + bb[c + 3];
      ushort4 uh, ul;
      uh.x = f2bf(n0); ul.x = f2bf(n0 - bf2f(uh.x));
      uh.y = f2bf(n1); ul.y = f2bf(n1 - bf2f(uh.y));
      uh.z = f2bf(n2); ul.z = f2bf(n2 - bf2f(uh.z));
      uh.w = f2bf(n3); ul.w = f2bf(n3 - bf2f(uh.w));
      *(ushort4*)&XH[tt * 104 + c] = uh;
      *(ushort4*)&XL[tt * 104 + c] = ul;
    }
  }

  s8v axh[3], axl[3];
  #pragma unroll
  for (int kt = 0; kt < 3; ++kt) {
    axh[kt] = *(const s8v*)&XH[(m0 + ln) * 104 + kt * 32 + 8 * gq];
    axl[kt] = *(const s8v*)&XL[(m0 + ln) * 104 + kt * 32 + 8 * gq];
  }

  f4v oacc[6];
  #pragma unroll
  for (int nt = 0; nt < 6; ++nt) oacc[nt] = (f4v){0.f, 0.f, 0.f, 0.f};

  ushort* Hh = HH[wave];
  ushort* Hl = HL[wave];

  for (int phq = 0; phq < 4; ++phq) {   // quarter of the 384 hidden cols
    f4v acc1[6];
    #pragma unroll
    for (int nt = 0; nt < 6; ++nt) acc1[nt] = (f4v){0.f, 0.f, 0.f, 0.f};

    // ---- fc1 quarter: 3 k-tiles, each staged once per block ----
    for (int kt = 0; kt < 3; ++kt) {
      __syncthreads();   // previous tile fully consumed
      for (int e = tid; e < 96 * 32; e += 512) {
        int kl = e / 96, cgl = e - kl * 96;          // global read coalesced in cgl
        float f = fc1_w[(size_t)(kt * 32 + kl) * 384 + phq * 96 + cgl];
        ushort h = f2bf(f);
        WH[cgl * 40 + kl] = h;
        WL[cgl * 40 + kl] = f2bf(f - bf2f(h));
      }
      __syncthreads();
      #pragma unroll
      for (int nt = 0; nt < 6; ++nt) {
        s8v Bh = *(const s8v*)&WH[(nt * 16 + ln) * 40 + 8 * gq];
        s8v Bl = *(const s8v*)&WL[(nt * 16 + ln) * 40 + 8 * gq];
        f4v a = acc1[nt];
        a = mfma16(axh[kt], Bh, a);
        a = mfma16(axl[kt], Bh, a);
        a = mfma16(axh[kt], Bl, a);
        acc1[nt] = a;
      }
    }

    // ---- bias + exact gelu -> per-wave H quarter (hi/lo) ----
    #pragma unroll
    for (int nt = 0; nt < 6; ++nt) {
      int cg = phq * 96 + nt * 16 + ln;
      float fb = fc1_b[cg];
      #pragma unroll
      for (int r = 0; r < 4; ++r) {
        float u = acc1[nt][r] + fb;
        float ge = 0.5f * u * (1.f + erff(u * 0.70710678118654752f));
        ushort hi = f2bf(ge), lo = f2bf(ge - bf2f(hi));
        Hh[(4 * gq + r) * 104 + nt * 16 + ln] = hi;
        Hl[(4 * gq + r) * 104 + nt * 16 + ln] = lo;
      }
    }

    // ---- fc2 partial over this quarter's K range ----
    for (int kk = 0; kk < 3; ++kk) {
      __syncthreads();
      for (int e = tid; e < 96 * 32; e += 512) {
        int kl = e / 96, c = e - kl * 96;            // coalesced in c
        float f = fc2_w[(size_t)(phq * 96 + kk * 32 + kl) * 96 + c];
        ushort h = f2bf(f);
        WH[c * 40 + kl] = h;
        WL[c * 40 + kl] = f2bf(f - bf2f(h));
      }
      __syncthreads();
      s8v Ahh = *(const s8v*)&Hh[ln * 104 + kk * 32 + 8 * gq];
      s8v Ahl = *(const s8v*)&Hl[ln * 104 + kk * 32 + 8 * gq];
      #pragma unroll
      for (int nt = 0; nt < 6; ++nt) {
        s8v Bh = *(const s8v*)&WH[(nt * 16 + ln) * 40 + 8 * gq];
        s8v Bl = *(const s8v*)&WL[(nt * 16 + ln) * 40 + 8 * gq];
        f4v o = oacc[nt];
        o = mfma16(Ahh, Bh, o);
        o = mfma16(Ahl, Bh, o);
        o = mfma16(Ahh, Bl, o);
        oacc[nt] = o;
      }
    }
  }

  // ---- residual + write ----
  #pragma unroll
  for (int nt = 0; nt < 6; ++nt) {
    int c = nt * 16 + ln;
    float fb = fc2_b[c];
    #pragma unroll
    for (int r = 0; r < 4; ++r) {
      int m = m0 + 4 * gq + r;
      size_t a = base + (size_t)m * 96 + c;
      io[a] = io[a] + oacc[nt][r] + fb;
    }
  }
}

extern "C" void kernel_launch(void* const* d_in, const int* in_sizes, int n_in,
                              void* d_out, int out_size, void* d_ws, size_t ws_size,
                              hipStream_t stream) {
  const float* x      = (const float*)d_in[0];
  const float* qkv_w  = (const float*)d_in[1];
  const float* qkv_b  = (const float*)d_in[2];
  const float* proj_w = (const float*)d_in[3];
  const float* proj_b = (const float*)d_in[4];
  const float* rpb    = (const float*)d_in[5];
  const float* n2g    = (const float*)d_in[6];
  const float* n2b    = (const float*)d_in[7];
  const float* fc1_w  = (const float*)d_in[8];
  const float* fc1_b  = (const float*)d_in[9];
  const float* fc2_w  = (const float*)d_in[10];
  const float* fc2_b  = (const float*)d_in[11];
  float* out = (float*)d_out;

  // K1: window attention -> writes xr (pre-MLP) into d_out (full overwrite)
  win_attn_mfma<<<8192, 256, 0, stream>>>(x, qkv_w, qkv_b, proj_w, proj_b, rpb, out);
  // K2: LN + MLP + residual, in-place on d_out (128 tokens/block)
  mlp_mfma<<<3136, 512, 0, stream>>>(out, n2g, n2b, fc1_w, fc1_b, fc2_w, fc2_b);
}

// Round 12
// 2262.539 us; speedup vs baseline: 2.1306x; 1.3023x over previous
//
#include <hip/hip_runtime.h>
#include <math.h>

// B=8, H=W=224, C=96, NH=3, HD=32, WS=7, SHIFT=3, N=49
// windows: 8192; tokens: 401408.  ZERO d_ws usage.
// Certified MFMA operand rule (r1/r2/r8/r10 vs r5/r6/r7/r9 evidence): operands
// must be read as whole 16B vectors from LDS/global written via plain scalar
// stores. NEVER assemble ext-vector fragments element-wise in registers.
// Weight tiles: cooperatively staged [cols][k pad 40] hi/lo LDS tiles (r10 MLP
// pattern, certified); accumulation order preserved -> bitwise-stable output.

typedef short s8v __attribute__((ext_vector_type(8)));
typedef float f4v __attribute__((ext_vector_type(4)));

__device__ __forceinline__ ushort f2bf(float f) {
  union { float f; unsigned u; } v; v.f = f;
  unsigned r = v.u + 0x7fffu + ((v.u >> 16) & 1u);
  return (ushort)(r >> 16);
}
__device__ __forceinline__ float bf2f(ushort u) {
  union { unsigned u; float f; } v; v.u = ((unsigned)u) << 16;
  return v.f;
}
__device__ __forceinline__ f4v mfma16(s8v a, s8v b, f4v c) {
  return __builtin_amdgcn_mfma_f32_16x16x32_bf16(a, b, c, 0, 0, 0);
}

// ---------------- window attention: staged weights, split-bf16 ----------------
// 1 window/block, 4 waves; wave w owns token-rows m = [16w, 16w+16).
__global__ __launch_bounds__(256) void win_attn_mfma(
    const float* __restrict__ x,
    const float* __restrict__ qkv_w, const float* __restrict__ qkv_b,
    const float* __restrict__ proj_w, const float* __restrict__ proj_b,
    const float* __restrict__ rpb,
    float* __restrict__ xr)
{
  __shared__ ushort XWH[64 * 104];  // X hi; aliased as P hi after phase 1
  __shared__ ushort XWL[64 * 104];  // X lo; aliased as P lo
  __shared__ ushort QH[64 * 104];   // Q hi (scaled); O hi overwrites per-head
  __shared__ ushort QL[64 * 104];   // Q lo
  __shared__ ushort KH[64 * 104];   // K hi
  __shared__ ushort KL2[64 * 104];  // K lo
  __shared__ ushort VTH[96 * 72];   // V^T hi: [d][t]
  __shared__ ushort VTL[96 * 72];   // V^T lo
  __shared__ ushort WSH[96 * 40];   // staged weight tile hi: [col][k pad 40]
  __shared__ ushort WSL[96 * 40];   // staged weight tile lo

  ushort* PH = XWH;  // [64][72] P hi (X dead after phase-1 consumption)
  ushort* PL = XWL;

  const int tid = threadIdx.x;
  const int wave = tid >> 6, lane = tid & 63, g = lane >> 4, ln = lane & 15;
  const int m0 = 16 * wave;
  const int win = blockIdx.x;
  const int b = win >> 10, rem = win & 1023, wh = rem >> 5, ww = rem & 31;
  const float SCALE = 0.17677669529663687f;

  // ---- phase 0: load window (shift -3), rows >=49 zero, exact hi/lo split ----
  for (int idx = tid; idx < 64 * 24; idx += 256) {
    int t = idx / 24, c4 = (idx % 24) * 4;
    float4 v = make_float4(0.f, 0.f, 0.f, 0.f);
    if (t < 49) {
      int i = t / 7, j = t % 7;
      int hh = wh * 7 + i + 3; if (hh >= 224) hh -= 224;
      int wc = ww * 7 + j + 3; if (wc >= 224) wc -= 224;
      v = *(const float4*)(x + ((size_t)(b * 224 + hh) * 224 + wc) * 96 + c4);
    }
    ushort4 uh, ul;
    uh.x = f2bf(v.x); ul.x = f2bf(v.x - bf2f(uh.x));
    uh.y = f2bf(v.y); ul.y = f2bf(v.y - bf2f(uh.y));
    uh.z = f2bf(v.z); ul.z = f2bf(v.z - bf2f(uh.z));
    uh.w = f2bf(v.w); ul.w = f2bf(v.w - bf2f(uh.w));
    *(ushort4*)&XWH[t * 104 + c4] = uh;
    *(ushort4*)&XWL[t * 104 + c4] = ul;
  }
  __syncthreads();

  // ---- phase 1: qkv GEMM; col-group grp (0=Q,1=K,2=V), staged k-tiles ----
  {
    s8v axh[3], axl[3];
    #pragma unroll
    for (int kt = 0; kt < 3; ++kt) {
      axh[kt] = *(const s8v*)&XWH[(m0 + ln) * 104 + kt * 32 + 8 * g];
      axl[kt] = *(const s8v*)&XWL[(m0 + ln) * 104 + kt * 32 + 8 * g];
    }
    for (int grp = 0; grp < 3; ++grp) {
      f4v acc[6];
      #pragma unroll
      for (int ctl = 0; ctl < 6; ++ctl) acc[ctl] = (f4v){0.f, 0.f, 0.f, 0.f};
      for (int kt = 0; kt < 3; ++kt) {
        __syncthreads();   // previous tile fully consumed
        for (int e = tid; e < 96 * 32; e += 256) {
          int kl = e / 96, cgl = e - kl * 96;   // global read coalesced in cgl
          float f = qkv_w[(size_t)(kt * 32 + kl) * 288 + grp * 96 + cgl];
          ushort h = f2bf(f);
          WSH[cgl * 40 + kl] = h;
          WSL[cgl * 40 + kl] = f2bf(f - bf2f(h));
        }
        __syncthreads();
        #pragma unroll
        for (int ctl = 0; ctl < 6; ++ctl) {
          s8v Bh = *(const s8v*)&WSH[(ctl * 16 + ln) * 40 + 8 * g];
          s8v Bl = *(const s8v*)&WSL[(ctl * 16 + ln) * 40 + 8 * g];
          f4v a = acc[ctl];
          a = mfma16(axh[kt], Bh, a);
          a = mfma16(axl[kt], Bh, a);
          a = mfma16(axh[kt], Bl, a);
          acc[ctl] = a;
        }
      }
      // write segment grp (wave-private m rows / V^T columns)
      #pragma unroll
      for (int ctl = 0; ctl < 6; ++ctl) {
        int cc = ctl * 16 + ln;
        float bias = qkv_b[grp * 96 + cc];
        #pragma unroll
        for (int r = 0; r < 4; ++r) {
          int m = m0 + 4 * g + r;
          float val = acc[ctl][r] + bias;
          ushort hi, lo;
          if (grp == 0) {
            val *= SCALE;
            hi = f2bf(val); lo = f2bf(val - bf2f(hi));
            QH[m * 104 + cc] = hi; QL[m * 104 + cc] = lo;
          } else if (grp == 1) {
            hi = f2bf(val); lo = f2bf(val - bf2f(hi));
            KH[m * 104 + cc] = hi; KL2[m * 104 + cc] = lo;
          } else {
            hi = f2bf(val); lo = f2bf(val - bf2f(hi));
            VTH[cc * 72 + m] = hi; VTL[cc * 72 + m] = lo;
          }
        }
      }
    }
  }
  __syncthreads();  // K, V^T shared across waves; X space becomes P space

  // ---- phase 2: per head: S = Q·K^T -> softmax -> O = P·V ----
  for (int h3 = 0; h3 < 3; ++h3) {
    const int hb = 32 * h3;
    s8v aqh = *(const s8v*)&QH[(m0 + ln) * 104 + hb + 8 * g];
    s8v aql = *(const s8v*)&QL[(m0 + ln) * 104 + hb + 8 * g];
    f4v sv[4];
    #pragma unroll
    for (int st = 0; st < 4; ++st) {
      s8v bkh = *(const s8v*)&KH[(st * 16 + ln) * 104 + hb + 8 * g];
      s8v bkl = *(const s8v*)&KL2[(st * 16 + ln) * 104 + hb + 8 * g];
      f4v z = {0.f, 0.f, 0.f, 0.f};
      z = mfma16(aqh, bkh, z);
      z = mfma16(aql, bkh, z);
      z = mfma16(aqh, bkl, z);
      sv[st] = z;  // S[m0+4g+r][st*16+ln]
    }
    #pragma unroll
    for (int r = 0; r < 4; ++r) {
      int m = m0 + 4 * g + r;
      bool mok = (m < 49);
      int mm = mok ? m : 0;
      int ti = mm / 7, tj = mm % 7;
      float mx = -1e30f;
      #pragma unroll
      for (int st = 0; st < 4; ++st) {
        int s = st * 16 + ln;
        float v = sv[st][r];
        if (s < 49 && mok) {
          int si = s / 7, sj = s % 7;
          v += rpb[((ti - si + 6) * 13 + (tj - sj + 6)) * 3 + h3];
        }
        if (s >= 49) v = -1e30f;
        sv[st][r] = v;
        mx = fmaxf(mx, v);
      }
      #pragma unroll
      for (int o = 1; o < 16; o <<= 1) mx = fmaxf(mx, __shfl_xor(mx, o));
      float sum = 0.f;
      #pragma unroll
      for (int st = 0; st < 4; ++st) {
        int s = st * 16 + ln;
        float e = (s < 49) ? __expf(sv[st][r] - mx) : 0.f;
        sv[st][r] = e; sum += e;
      }
      #pragma unroll
      for (int o = 1; o < 16; o <<= 1) sum += __shfl_xor(sum, o);
      float inv = 1.f / sum;
      #pragma unroll
      for (int st = 0; st < 4; ++st) {
        int s = st * 16 + ln;
        float pv = sv[st][r] * inv;
        ushort hi = f2bf(pv), lo = f2bf(pv - bf2f(hi));
        PH[m * 72 + s] = hi; PL[m * 72 + s] = lo;   // wave-private rows
      }
    }
    // PV: A = P rows (own), B = V^T fragment
    s8v aph[2], apl[2];
    #pragma unroll
    for (int ks = 0; ks < 2; ++ks) {
      aph[ks] = *(const s8v*)&PH[(m0 + ln) * 72 + ks * 32 + 8 * g];
      apl[ks] = *(const s8v*)&PL[(m0 + ln) * 72 + ks * 32 + 8 * g];
    }
    #pragma unroll
    for (int dt = 0; dt < 2; ++dt) {
      f4v oa = {0.f, 0.f, 0.f, 0.f};
      #pragma unroll
      for (int ks = 0; ks < 2; ++ks) {
        const int vrow = (hb + dt * 16 + ln) * 72 + ks * 32 + 8 * g;
        s8v bvh = *(const s8v*)&VTH[vrow];
        s8v bvl = *(const s8v*)&VTL[vrow];
        oa = mfma16(aph[ks], bvh, oa);
        oa = mfma16(apl[ks], bvh, oa);
        oa = mfma16(aph[ks], bvl, oa);
      }
      #pragma unroll
      for (int r = 0; r < 4; ++r) {
        int m = m0 + 4 * g + r;
        ushort hi = f2bf(oa[r]), lo = f2bf(oa[r] - bf2f(hi));
        QH[m * 104 + hb + dt * 16 + ln] = hi;  // O overwrites Q (own rows)
        QL[m * 104 + hb + dt * 16 + ln] = lo;
      }
    }
  }

  // ---- phase 3: proj (staged k-tiles) + scatter (reverse shift) ----
  {
    s8v aoh[3], aol[3];
    #pragma unroll
    for (int kb = 0; kb < 3; ++kb) {
      aoh[kb] = *(const s8v*)&QH[(m0 + ln) * 104 + kb * 32 + 8 * g];
      aol[kb] = *(const s8v*)&QL[(m0 + ln) * 104 + kb * 32 + 8 * g];
    }
    f4v acc[6];
    #pragma unroll
    for (int nt = 0; nt < 6; ++nt) acc[nt] = (f4v){0.f, 0.f, 0.f, 0.f};
    for (int kb = 0; kb < 3; ++kb) {
      __syncthreads();
      for (int e = tid; e < 96 * 32; e += 256) {
        int kl = e / 96, c = e - kl * 96;   // coalesced in c
        float f = proj_w[(size_t)(kb * 32 + kl) * 96 + c];
        ushort h = f2bf(f);
        WSH[c * 40 + kl] = h;
        WSL[c * 40 + kl] = f2bf(f - bf2f(h));
      }
      __syncthreads();
      #pragma unroll
      for (int nt = 0; nt < 6; ++nt) {
        s8v Bh = *(const s8v*)&WSH[(nt * 16 + ln) * 40 + 8 * g];
        s8v Bl = *(const s8v*)&WSL[(nt * 16 + ln) * 40 + 8 * g];
        f4v a = acc[nt];
        a = mfma16(aoh[kb], Bh, a);
        a = mfma16(aol[kb], Bh, a);
        a = mfma16(aoh[kb], Bl, a);
        acc[nt] = a;
      }
    }
    #pragma unroll
    for (int nt = 0; nt < 6; ++nt) {
      int c = nt * 16 + ln;
      float pb = proj_b[c];
      #pragma unroll
      for (int r = 0; r < 4; ++r) {
        int m = m0 + 4 * g + r;
        if (m < 49) {
          int i = m / 7, j = m % 7;
          int hh = wh * 7 + i + 3; if (hh >= 224) hh -= 224;
          int wv = ww * 7 + j + 3; if (wv >= 224) wv -= 224;
          xr[((size_t)(b * 224 + hh) * 224 + wv) * 96 + c] = acc[nt][r] + pb;
        }
      }
    }
  }
}

// ---------------- LN + MLP (round-10 GREEN kernel, verbatim) ----------------
// 128 tokens/block, 8 waves; wave w owns tokens [16w,16w+16).
__global__ __launch_bounds__(512) void mlp_mfma(
    float* __restrict__ io, const float* __restrict__ gg, const float* __restrict__ bb,
    const float* __restrict__ fc1_w, const float* __restrict__ fc1_b,
    const float* __restrict__ fc2_w, const float* __restrict__ fc2_b)
{
  __shared__ ushort XH[128 * 104], XL[128 * 104];      // normalized tokens hi/lo
  __shared__ ushort HH[8][16 * 104], HL[8][16 * 104];  // per-wave quarter gelu(fc1)
  __shared__ ushort WH[96 * 40], WL[96 * 40];          // staged weight tile

  const int tid = threadIdx.x;
  const int wave = tid >> 6, lane = tid & 63, gq = lane >> 4, ln = lane & 15;
  const int m0 = wave * 16;
  const size_t base = (size_t)blockIdx.x * 128 * 96;

  // LN: 4 threads/token (wave-private tokens; in-wave LDS write->read only)
  {
    const int tt = tid >> 2, q = tid & 3;
    const float* xp = io + base + (size_t)tt * 96 + q * 24;
    float4 v[6];
    #pragma unroll
    for (int i = 0; i < 6; ++i) v[i] = *(const float4*)(xp + i * 4);
    float s = 0.f, s2 = 0.f;
    #pragma unroll
    for (int i = 0; i < 6; ++i) {
      s  += v[i].x + v[i].y + v[i].z + v[i].w;
      s2 += v[i].x * v[i].x + v[i].y * v[i].y + v[i].z * v[i].z + v[i].w * v[i].w;
    }
    s  += __shfl_xor(s, 1);  s  += __shfl_xor(s, 2);
    s2 += __shfl_xor(s2, 1); s2 += __shfl_xor(s2, 2);
    float mu  = s * (1.f / 96.f);
    float inv = rsqrtf(s2 * (1.f / 96.f) - mu * mu + 1e-5f);
    #pragma unroll
    for (int i = 0; i < 6; ++i) {
      int c = q * 24 + i * 4;
      float n0 = (v[i].x - mu) * inv * gg[c + 0] + bb[c + 0];
      float n1 = (v[i].y - mu) * inv * gg[c + 1] + bb[c + 1];
      float n2 = (v[i].z - mu) * inv * gg[c + 2] + bb[c + 2];
      float n3 = (v[i].w - mu) * inv * gg[c + 3] + bb[c + 3];
      ushort4 uh, ul;
      uh.x = f2bf(n0); ul.x = f2bf(n0 - bf2f(uh.x));
      uh.y = f2bf(n1); ul.y = f2bf(n1 - bf2f(uh.y));
      uh.z = f2bf(n2); ul.z = f2bf(n2 - bf2f(uh.z));
      uh.w = f2bf(n3); ul.w = f2bf(n3 - bf2f(uh.w));
      *(ushort4*)&XH[tt * 104 + c] = uh;
      *(ushort4*)&XL[tt * 104 + c] = ul;
    }
  }

  s8v axh[3], axl[3];
  #pragma unroll
  for (int kt = 0; kt < 3; ++kt) {
    axh[kt] = *(const s8v*)&XH[(m0 + ln) * 104 + kt * 32 + 8 * gq];
    axl[kt] = *(const s8v*)&XL[(m0 + ln) * 104 + kt * 32 + 8 * gq];
  }

  f4v oacc[6];
  #pragma unroll
  for (int nt = 0; nt < 6; ++nt) oacc[nt] = (f4v){0.f, 0.f, 0.f, 0.f};

  ushort* Hh = HH[wave];
  ushort* Hl = HL[wave];

  for (int phq = 0; phq < 4; ++phq) {   // quarter of the 384 hidden cols
    f4v acc1[6];
    #pragma unroll
    for (int nt = 0; nt < 6; ++nt) acc1[nt] = (f4v){0.f, 0.f, 0.f, 0.f};

    // ---- fc1 quarter: 3 k-tiles, each staged once per block ----
    for (int kt = 0; kt < 3; ++kt) {
      __syncthreads();   // previous tile fully consumed
      for (int e = tid; e < 96 * 32; e += 512) {
        int kl = e / 96, cgl = e - kl * 96;          // global read coalesced in cgl
        float f = fc1_w[(size_t)(kt * 32 + kl) * 384 + phq * 96 + cgl];
        ushort h = f2bf(f);
        WH[cgl * 40 + kl] = h;
        WL[cgl * 40 + kl] = f2bf(f - bf2f(h));
      }
      __syncthreads();
      #pragma unroll
      for (int nt = 0; nt < 6; ++nt) {
        s8v Bh = *(const s8v*)&WH[(nt * 16 + ln) * 40 + 8 * gq];
        s8v Bl = *(const s8v*)&WL[(nt * 16 + ln) * 40 + 8 * gq];
        f4v a = acc1[nt];
        a = mfma16(axh[kt], Bh, a);
        a = mfma16(axl[kt], Bh, a);
        a = mfma16(axh[kt], Bl, a);
        acc1[nt] = a;
      }
    }

    // ---- bias + exact gelu -> per-wave H quarter (hi/lo) ----
    #pragma unroll
    for (int nt = 0; nt < 6; ++nt) {
      int cg = phq * 96 + nt * 16 + ln;
      float fb = fc1_b[cg];
      #pragma unroll
      for (int r = 0; r < 4; ++r) {
        float u = acc1[nt][r] + fb;
        float ge = 0.5f * u * (1.f + erff(u * 0.70710678118654752f));
        ushort hi = f2bf(ge), lo = f2bf(ge - bf2f(hi));
        Hh[(4 * gq + r) * 104 + nt * 16 + ln] = hi;
        Hl[(4 * gq + r) * 104 + nt * 16 + ln] = lo;
      }
    }

    // ---- fc2 partial over this quarter's K range ----
    for (int kk = 0; kk < 3; ++kk) {
      __syncthreads();
      for (int e = tid; e < 96 * 32; e += 512) {
        int kl = e / 96, c = e - kl * 96;            // coalesced in c
        float f = fc2_w[(size_t)(phq * 96 + kk * 32 + kl) * 96 + c];
        ushort h = f2bf(f);
        WH[c * 40 + kl] = h;
        WL[c * 40 + kl] = f2bf(f - bf2f(h));
      }
      __syncthreads();
      s8v Ahh = *(const s8v*)&Hh[ln * 104 + kk * 32 + 8 * gq];
      s8v Ahl = *(const s8v*)&Hl[ln * 104 + kk * 32 + 8 * gq];
      #pragma unroll
      for (int nt = 0; nt < 6; ++nt) {
        s8v Bh = *(const s8v*)&WH[(nt * 16 + ln) * 40 + 8 * gq];
        s8v Bl = *(const s8v*)&WL[(nt * 16 + ln) * 40 + 8 * gq];
        f4v o = oacc[nt];
        o = mfma16(Ahh, Bh, o);
        o = mfma16(Ahl, Bh, o);
        o = mfma16(Ahh, Bl, o);
        oacc[nt] = o;
      }
    }
  }

  // ---- residual + write ----
  #pragma unroll
  for (int nt = 0; nt < 6; ++nt) {
    int c = nt * 16 + ln;
    float fb = fc2_b[c];
    #pragma unroll
    for (int r = 0; r < 4; ++r) {
      int m = m0 + 4 * gq + r;
      size_t a = base + (size_t)m * 96 + c;
      io[a] = io[a] + oacc[nt][r] + fb;
    }
  }
}

extern "C" void kernel_launch(void* const* d_in, const int* in_sizes, int n_in,
                              void* d_out, int out_size, void* d_ws, size_t ws_size,
                              hipStream_t stream) {
  const float* x      = (const float*)d_in[0];
  const float* qkv_w  = (const float*)d_in[1];
  const float* qkv_b  = (const float*)d_in[2];
  const float* proj_w = (const float*)d_in[3];
  const float* proj_b = (const float*)d_in[4];
  const float* rpb    = (const float*)d_in[5];
  const float* n2g    = (const float*)d_in[6];
  const float* n2b    = (const float*)d_in[7];
  const float* fc1_w  = (const float*)d_in[8];
  const float* fc1_b  = (const float*)d_in[9];
  const float* fc2_w  = (const float*)d_in[10];
  const float* fc2_b  = (const float*)d_in[11];
  float* out = (float*)d_out;

  // K1: window attention -> writes xr (pre-MLP) into d_out (full overwrite)
  win_attn_mfma<<<8192, 256, 0, stream>>>(x, qkv_w, qkv_b, proj_w, proj_b, rpb, out);
  // K2: LN + MLP + residual, in-place on d_out (128 tokens/block)
  mlp_mfma<<<3136, 512, 0, stream>>>(out, n2g, n2b, fc1_w, fc1_b, fc2_w, fc2_b);
}

// Round 13
// 995.572 us; speedup vs baseline: 4.8421x; 2.2726x over previous
//
#include <hip/hip_runtime.h>
#include <math.h>

// B=8, H=W=224, C=96, NH=3, HD=32, WS=7, SHIFT=3, N=49
// windows: 8192; tokens: 401408.  ZERO d_ws usage.
// Plain bf16 numerics (round-2-certified, 1.22e-3 < 3.63e-3 threshold).
// Certified MFMA operand rule: operands read as whole 16B vectors from LDS
// written via plain scalar stores. No register-assembled fragments.
// LDS aliasing: attn X region time-shares with weight staging (ph 1,3) and P (ph 2).

typedef short s8v __attribute__((ext_vector_type(8)));
typedef float f4v __attribute__((ext_vector_type(4)));

__device__ __forceinline__ ushort f2bf(float f) {
  union { float f; unsigned u; } v; v.f = f;
  unsigned r = v.u + 0x7fffu + ((v.u >> 16) & 1u);
  return (ushort)(r >> 16);
}
__device__ __forceinline__ f4v mfma16(s8v a, s8v b, f4v c) {
  return __builtin_amdgcn_mfma_f32_16x16x32_bf16(a, b, c, 0, 0, 0);
}

// ---------------- window attention: plain bf16, staged weights ----------------
// 1 window/block, 4 waves; wave w owns token-rows m = [16w, 16w+16).
// LDS 52.5 KB -> 3 blocks/CU.
__global__ __launch_bounds__(256, 2) void win_attn_mfma(
    const float* __restrict__ x,
    const float* __restrict__ qkv_w, const float* __restrict__ qkv_b,
    const float* __restrict__ proj_w, const float* __restrict__ proj_b,
    const float* __restrict__ rpb,
    float* __restrict__ xr)
{
  __shared__ ushort R1[64 * 104];  // X (ph0-1 fragments); then WS [96][40] (ph1,3) / P [64][72] (ph2)
  __shared__ ushort QO[64 * 104];  // Q (scaled); O overwrites per-head col range
  __shared__ ushort KS[64 * 104];  // K
  __shared__ ushort VT[96 * 72];   // V^T: [d][t]

  ushort* WS = R1;   // [96][40] weight staging tile
  ushort* P  = R1;   // [64][72] probabilities (wave-private rows)

  const int tid = threadIdx.x;
  const int wave = tid >> 6, lane = tid & 63, g = lane >> 4, ln = lane & 15;
  const int m0 = 16 * wave;
  const int win = blockIdx.x;
  const int b = win >> 10, rem = win & 1023, wh = rem >> 5, ww = rem & 31;
  const float SCALE = 0.17677669529663687f;

  // ---- phase 0: load window (shift -3), rows >=49 zero, to bf16 ----
  for (int idx = tid; idx < 64 * 24; idx += 256) {
    int t = idx / 24, c4 = (idx % 24) * 4;
    float4 v = make_float4(0.f, 0.f, 0.f, 0.f);
    if (t < 49) {
      int i = t / 7, j = t % 7;
      int hh = wh * 7 + i + 3; if (hh >= 224) hh -= 224;
      int wc = ww * 7 + j + 3; if (wc >= 224) wc -= 224;
      v = *(const float4*)(x + ((size_t)(b * 224 + hh) * 224 + wc) * 96 + c4);
    }
    ushort4 u;
    u.x = f2bf(v.x); u.y = f2bf(v.y); u.z = f2bf(v.z); u.w = f2bf(v.w);
    *(ushort4*)&R1[t * 104 + c4] = u;
  }
  __syncthreads();

  // ---- phase 1: qkv GEMM; grp (0=Q,1=K,2=V) x staged k-tiles ----
  {
    s8v ax[3];
    #pragma unroll
    for (int kt = 0; kt < 3; ++kt)
      ax[kt] = *(const s8v*)&R1[(m0 + ln) * 104 + kt * 32 + 8 * g];

    for (int grp = 0; grp < 3; ++grp) {
      f4v acc[6];
      #pragma unroll
      for (int ctl = 0; ctl < 6; ++ctl) acc[ctl] = (f4v){0.f, 0.f, 0.f, 0.f};
      for (int kt = 0; kt < 3; ++kt) {
        __syncthreads();   // fragments loaded (1st iter) / prev tile consumed; X region now free
        for (int e = tid; e < 96 * 32; e += 256) {
          int kl = e / 96, cgl = e - kl * 96;   // global read coalesced in cgl
          WS[cgl * 40 + kl] = f2bf(qkv_w[(size_t)(kt * 32 + kl) * 288 + grp * 96 + cgl]);
        }
        __syncthreads();
        #pragma unroll
        for (int ctl = 0; ctl < 6; ++ctl) {
          s8v Bw = *(const s8v*)&WS[(ctl * 16 + ln) * 40 + 8 * g];
          acc[ctl] = mfma16(ax[kt], Bw, acc[ctl]);
        }
      }
      // write segment grp (wave-private m rows / V^T columns)
      #pragma unroll
      for (int ctl = 0; ctl < 6; ++ctl) {
        int cc = ctl * 16 + ln;
        float bias = qkv_b[grp * 96 + cc];
        #pragma unroll
        for (int r = 0; r < 4; ++r) {
          int m = m0 + 4 * g + r;
          float val = acc[ctl][r] + bias;
          if      (grp == 0) QO[m * 104 + cc] = f2bf(val * SCALE);
          else if (grp == 1) KS[m * 104 + cc] = f2bf(val);
          else               VT[cc * 72 + m] = f2bf(val);
        }
      }
    }
  }
  __syncthreads();  // K, V^T shared across waves; WS region becomes P space

  // ---- phase 2: per head: S = Q·K^T -> softmax -> O = P·V ----
  for (int h3 = 0; h3 < 3; ++h3) {
    const int hb = 32 * h3;
    s8v aq = *(const s8v*)&QO[(m0 + ln) * 104 + hb + 8 * g];
    f4v sv[4];
    #pragma unroll
    for (int st = 0; st < 4; ++st) {
      s8v bk = *(const s8v*)&KS[(st * 16 + ln) * 104 + hb + 8 * g];
      f4v z = {0.f, 0.f, 0.f, 0.f};
      sv[st] = mfma16(aq, bk, z);  // S[m0+4g+r][st*16+ln]
    }
    #pragma unroll
    for (int r = 0; r < 4; ++r) {
      int m = m0 + 4 * g + r;
      bool mok = (m < 49);
      int mm = mok ? m : 0;
      int ti = mm / 7, tj = mm % 7;
      float mx = -1e30f;
      #pragma unroll
      for (int st = 0; st < 4; ++st) {
        int s = st * 16 + ln;
        float v = sv[st][r];
        if (s < 49 && mok) {
          int si = s / 7, sj = s % 7;
          v += rpb[((ti - si + 6) * 13 + (tj - sj + 6)) * 3 + h3];
        }
        if (s >= 49) v = -1e30f;
        sv[st][r] = v;
        mx = fmaxf(mx, v);
      }
      #pragma unroll
      for (int o = 1; o < 16; o <<= 1) mx = fmaxf(mx, __shfl_xor(mx, o));
      float sum = 0.f;
      #pragma unroll
      for (int st = 0; st < 4; ++st) {
        int s = st * 16 + ln;
        float e = (s < 49) ? __expf(sv[st][r] - mx) : 0.f;
        sv[st][r] = e; sum += e;
      }
      #pragma unroll
      for (int o = 1; o < 16; o <<= 1) sum += __shfl_xor(sum, o);
      float inv = 1.f / sum;
      #pragma unroll
      for (int st = 0; st < 4; ++st) {
        int s = st * 16 + ln;
        P[m * 72 + s] = f2bf(sv[st][r] * inv);   // wave-private rows
      }
    }
    // PV: A = P rows (own), B = V^T fragment
    s8v ap[2];
    #pragma unroll
    for (int ks = 0; ks < 2; ++ks)
      ap[ks] = *(const s8v*)&P[(m0 + ln) * 72 + ks * 32 + 8 * g];
    #pragma unroll
    for (int dt = 0; dt < 2; ++dt) {
      f4v oa = {0.f, 0.f, 0.f, 0.f};
      #pragma unroll
      for (int ks = 0; ks < 2; ++ks) {
        s8v bv = *(const s8v*)&VT[(hb + dt * 16 + ln) * 72 + ks * 32 + 8 * g];
        oa = mfma16(ap[ks], bv, oa);
      }
      #pragma unroll
      for (int r = 0; r < 4; ++r) {
        int m = m0 + 4 * g + r;
        QO[m * 104 + hb + dt * 16 + ln] = f2bf(oa[r]);  // O overwrites Q (own rows)
      }
    }
  }

  // ---- phase 3: proj (staged k-tiles) + scatter (reverse shift) ----
  {
    s8v ao[3];
    #pragma unroll
    for (int kb = 0; kb < 3; ++kb)
      ao[kb] = *(const s8v*)&QO[(m0 + ln) * 104 + kb * 32 + 8 * g];
    f4v acc[6];
    #pragma unroll
    for (int nt = 0; nt < 6; ++nt) acc[nt] = (f4v){0.f, 0.f, 0.f, 0.f};
    for (int kb = 0; kb < 3; ++kb) {
      __syncthreads();   // all waves done with P/VT reads before clobbering R1
      for (int e = tid; e < 96 * 32; e += 256) {
        int kl = e / 96, c = e - kl * 96;   // coalesced in c
        WS[c * 40 + kl] = f2bf(proj_w[(size_t)(kb * 32 + kl) * 96 + c]);
      }
      __syncthreads();
      #pragma unroll
      for (int nt = 0; nt < 6; ++nt) {
        s8v Bw = *(const s8v*)&WS[(nt * 16 + ln) * 40 + 8 * g];
        acc[nt] = mfma16(ao[kb], Bw, acc[nt]);
      }
    }
    #pragma unroll
    for (int nt = 0; nt < 6; ++nt) {
      int c = nt * 16 + ln;
      float pb = proj_b[c];
      #pragma unroll
      for (int r = 0; r < 4; ++r) {
        int m = m0 + 4 * g + r;
        if (m < 49) {
          int i = m / 7, j = m % 7;
          int hh = wh * 7 + i + 3; if (hh >= 224) hh -= 224;
          int wv = ww * 7 + j + 3; if (wv >= 224) wv -= 224;
          xr[((size_t)(b * 224 + hh) * 224 + wv) * 96 + c] = acc[nt][r] + pb;
        }
      }
    }
  }
}

// ---------------- LN + MLP: plain bf16, staged weights ----------------
// 128 tokens/block, 8 waves; wave w owns tokens [16w,16w+16).  LDS 59.5 KB.
__global__ __launch_bounds__(512, 4) void mlp_mfma(
    float* __restrict__ io, const float* __restrict__ gg, const float* __restrict__ bb,
    const float* __restrict__ fc1_w, const float* __restrict__ fc1_b,
    const float* __restrict__ fc2_w, const float* __restrict__ fc2_b)
{
  __shared__ ushort XN[128 * 104];     // normalized tokens (bf16)
  __shared__ ushort Hq[8][16 * 104];   // per-wave quarter gelu(fc1)
  __shared__ ushort WS[96 * 40];       // staged weight tile

  const int tid = threadIdx.x;
  const int wave = tid >> 6, lane = tid & 63, gq = lane >> 4, ln = lane & 15;
  const int m0 = wave * 16;
  const size_t base = (size_t)blockIdx.x * 128 * 96;

  // LN: 4 threads/token (wave-private tokens; in-wave LDS write->read only)
  {
    const int tt = tid >> 2, q = tid & 3;
    const float* xp = io + base + (size_t)tt * 96 + q * 24;
    float4 v[6];
    #pragma unroll
    for (int i = 0; i < 6; ++i) v[i] = *(const float4*)(xp + i * 4);
    float s = 0.f, s2 = 0.f;
    #pragma unroll
    for (int i = 0; i < 6; ++i) {
      s  += v[i].x + v[i].y + v[i].z + v[i].w;
      s2 += v[i].x * v[i].x + v[i].y * v[i].y + v[i].z * v[i].z + v[i].w * v[i].w;
    }
    s  += __shfl_xor(s, 1);  s  += __shfl_xor(s, 2);
    s2 += __shfl_xor(s2, 1); s2 += __shfl_xor(s2, 2);
    float mu  = s * (1.f / 96.f);
    float inv = rsqrtf(s2 * (1.f / 96.f) - mu * mu + 1e-5f);
    #pragma unroll
    for (int i = 0; i < 6; ++i) {
      int c = q * 24 + i * 4;
      ushort4 u;
      u.x = f2bf((v[i].x - mu) * inv * gg[c + 0] + bb[c + 0]);
      u.y = f2bf((v[i].y - mu) * inv * gg[c + 1] + bb[c + 1]);
      u.z = f2bf((v[i].z - mu) * inv * gg[c + 2] + bb[c + 2]);
      u.w = f2bf((v[i].w - mu) * inv * gg[c + 3] + bb[c + 3]);
      *(ushort4*)&XN[tt * 104 + c] = u;
    }
  }
  __syncthreads();   // XN ready before WS staging cadence begins (keeps barrier parity)

  s8v ax[3];
  #pragma unroll
  for (int kt = 0; kt < 3; ++kt)
    ax[kt] = *(const s8v*)&XN[(m0 + ln) * 104 + kt * 32 + 8 * gq];

  f4v oacc[6];
  #pragma unroll
  for (int nt = 0; nt < 6; ++nt) oacc[nt] = (f4v){0.f, 0.f, 0.f, 0.f};

  ushort* Hh = Hq[wave];

  for (int phq = 0; phq < 4; ++phq) {   // quarter of the 384 hidden cols
    f4v acc1[6];
    #pragma unroll
    for (int nt = 0; nt < 6; ++nt) acc1[nt] = (f4v){0.f, 0.f, 0.f, 0.f};

    // ---- fc1 quarter: 3 k-tiles staged once per block ----
    for (int kt = 0; kt < 3; ++kt) {
      __syncthreads();
      for (int e = tid; e < 96 * 32; e += 512) {
        int kl = e / 96, cgl = e - kl * 96;          // coalesced in cgl
        WS[cgl * 40 + kl] = f2bf(fc1_w[(size_t)(kt * 32 + kl) * 384 + phq * 96 + cgl]);
      }
      __syncthreads();
      #pragma unroll
      for (int nt = 0; nt < 6; ++nt) {
        s8v Bw = *(const s8v*)&WS[(nt * 16 + ln) * 40 + 8 * gq];
        acc1[nt] = mfma16(ax[kt], Bw, acc1[nt]);
      }
    }

    // ---- bias + exact gelu -> per-wave H quarter ----
    #pragma unroll
    for (int nt = 0; nt < 6; ++nt) {
      int cg = phq * 96 + nt * 16 + ln;
      float fb = fc1_b[cg];
      #pragma unroll
      for (int r = 0; r < 4; ++r) {
        float u = acc1[nt][r] + fb;
        float ge = 0.5f * u * (1.f + erff(u * 0.70710678118654752f));
        Hh[(4 * gq + r) * 104 + nt * 16 + ln] = f2bf(ge);
      }
    }

    // ---- fc2 partial over this quarter's K range ----
    for (int kk = 0; kk < 3; ++kk) {
      __syncthreads();
      for (int e = tid; e < 96 * 32; e += 512) {
        int kl = e / 96, c = e - kl * 96;            // coalesced in c
        WS[c * 40 + kl] = f2bf(fc2_w[(size_t)(phq * 96 + kk * 32 + kl) * 96 + c]);
      }
      __syncthreads();
      s8v Ah = *(const s8v*)&Hh[ln * 104 + kk * 32 + 8 * gq];
      #pragma unroll
      for (int nt = 0; nt < 6; ++nt) {
        s8v Bw = *(const s8v*)&WS[(nt * 16 + ln) * 40 + 8 * gq];
        oacc[nt] = mfma16(Ah, Bw, oacc[nt]);
      }
    }
  }

  // ---- residual + write ----
  #pragma unroll
  for (int nt = 0; nt < 6; ++nt) {
    int c = nt * 16 + ln;
    float fb = fc2_b[c];
    #pragma unroll
    for (int r = 0; r < 4; ++r) {
      int m = m0 + 4 * gq + r;
      size_t a = base + (size_t)m * 96 + c;
      io[a] = io[a] + oacc[nt][r] + fb;
    }
  }
}

extern "C" void kernel_launch(void* const* d_in, const int* in_sizes, int n_in,
                              void* d_out, int out_size, void* d_ws, size_t ws_size,
                              hipStream_t stream) {
  const float* x      = (const float*)d_in[0];
  const float* qkv_w  = (const float*)d_in[1];
  const float* qkv_b  = (const float*)d_in[2];
  const float* proj_w = (const float*)d_in[3];
  const float* proj_b = (const float*)d_in[4];
  const float* rpb    = (const float*)d_in[5];
  const float* n2g    = (const float*)d_in[6];
  const float* n2b    = (const float*)d_in[7];
  const float* fc1_w  = (const float*)d_in[8];
  const float* fc1_b  = (const float*)d_in[9];
  const float* fc2_w  = (const float*)d_in[10];
  const float* fc2_b  = (const float*)d_in[11];
  float* out = (float*)d_out;

  // K1: window attention -> writes xr (pre-MLP) into d_out (full overwrite)
  win_attn_mfma<<<8192, 256, 0, stream>>>(x, qkv_w, qkv_b, proj_w, proj_b, rpb, out);
  // K2: LN + MLP + residual, in-place on d_out (128 tokens/block)
  mlp_mfma<<<3136, 512, 0, stream>>>(out, n2g, n2b, fc1_w, fc1_b, fc2_w, fc2_b);
}